// Round 1
// 205.260 us; speedup vs baseline: 1.2419x; 1.2419x over previous
//
#include <hip/hip_runtime.h>

#define F 128
#define NEG_SLOPE 0.2f

typedef _Float16 f16_t;
typedef _Float16 f16x8 __attribute__((ext_vector_type(8)));
typedef _Float16 f16x2 __attribute__((ext_vector_type(2)));
typedef float f32x4 __attribute__((ext_vector_type(4)));

// ---------------- prep: composite matrices + projection vectors + cnt zero ----------------
__global__ __launch_bounds__(128) void prep_mats(
    const float* __restrict__ Wu, const float* __restrict__ Wr,
    const float* __restrict__ Ws, const float* __restrict__ Wn,
    const float* __restrict__ alu, const float* __restrict__ aru,
    const float* __restrict__ alr, const float* __restrict__ arr_,
    f16_t* __restrict__ Mtu, f16_t* __restrict__ Mtr, f16_t* __restrict__ Wts,
    float* __restrict__ wlu, float* __restrict__ wru,
    float* __restrict__ wlr, float* __restrict__ wrr,
    int* __restrict__ cnt, int N)
{
    int b = blockIdx.x;
    int tid = threadIdx.x;
    if (b < 256) {
        int k = b & 127;
        const float* W = (b < 128) ? Wu : Wr;
        f16_t* M = (b < 128) ? Mtu : Mtr;
        float acc = 0.f;
        for (int t = 0; t < F; t++) acc += W[k * F + t] * Wn[t * F + tid];
        M[tid * F + k] = (f16_t)acc;
    } else if (b < 384) {
        int c = b - 256;
        Wts[c * F + tid] = (f16_t)Ws[tid * F + c];
    } else if (b < 388) {
        int which = b - 384;
        const float* W = (which < 2) ? Wu : Wr;
        const float* a = (which == 0) ? alu : (which == 1) ? aru : (which == 2) ? alr : arr_;
        float acc = 0.f;
        for (int c = 0; c < F; c++) acc += W[tid * F + c] * a[c];
        float* o = (which == 0) ? wlu : (which == 1) ? wru : (which == 2) ? wlr : wrr;
        o[tid] = acc;
    } else {
        // zero cnt[0 .. 2N): N/2 int4s
        int idx = (b - 388) * 128 + tid;
        if (idx < N / 2) ((int4*)cnt)[idx] = make_int4(0, 0, 0, 0);
    }
}

// ---------------- merged: count+rank (XCD-partitioned) interleaved with MFMA cast/el ----------
// period-16 interleave: (b&8)==0 -> count block (part = b&7 == XCD, g = b>>4),
//                       (b&8)!=0 -> cast block  (fid = (b>>4)*8 + (b&7)).
// Count now RETURNS the per-bin rank and stores it to rank[e] (u16), making scatter atomic-free.

__global__ __launch_bounds__(256) void cast_count(
    const float* __restrict__ feat,
    const float* __restrict__ wlu, const float* __restrict__ wru,
    const float* __restrict__ wlr, const float* __restrict__ wrr,
    f16_t* __restrict__ featb,
    float* __restrict__ elu, float* __restrict__ eru,
    float* __restrict__ elr, float* __restrict__ err_,
    const int* __restrict__ dst_u, const int* __restrict__ dst_r,
    int* __restrict__ cnt, unsigned short* __restrict__ rank,
    int Eu, int Et, int N, int chunk, int n)
{
    int b = blockIdx.x;
    if ((b & 8) == 0) {
        // ---- count + rank ----
        int part = b & 7;
        int g = b >> 4;
        if (g >= 256) return;
        int rlo = (int)((long long)part * N >> 3);
        int rhi = (int)((long long)(part + 1) * N >> 3);
        int e0 = g * chunk;
        int e1 = e0 + chunk; if (e1 > Et) e1 = Et;
        int u1 = (e1 < Eu) ? e1 : Eu;        // u-type range [e0, u1)
        for (int e = e0 + (int)threadIdx.x; e < u1; e += 256) {
            int d = dst_u[e];
            if (d >= rlo && d < rhi) {
                int r = atomicAdd(&cnt[d], 1);
                rank[e] = (unsigned short)r;
            }
        }
        int r0 = (e0 > Eu) ? e0 : Eu;        // r-type range [r0, e1)
        for (int e = r0 + (int)threadIdx.x; e < e1; e += 256) {
            int d = dst_r[e - Eu];
            if (d >= rlo && d < rhi) {
                int r = atomicAdd(&cnt[N + d], 1);
                rank[e] = (unsigned short)r;
            }
        }
        return;
    }
    // ---- cast + el/er via MFMA: wave handles 16 rows ----
    int fid = (b >> 4) * 8 + (b & 7);
    int lane = threadIdx.x & 63;
    int wave = threadIdx.x >> 6;
    int lo = lane & 15, hi = lane >> 4;
    int base = fid * 64 + wave * 16;
    if (base >= n) return;
    int row = base + lo;
    if (row > n - 1) row = n - 1;
    const float* fp = feat + (size_t)row * F + hi * 8;
    f16_t* fb = featb + (size_t)row * F + hi * 8;
    const float* wsel = (lo == 0) ? wlu : (lo == 1) ? wru : (lo == 2) ? wlr : wrr;

    f32x4 acc = (f32x4){0.f, 0.f, 0.f, 0.f};
#pragma unroll
    for (int ks = 0; ks < 4; ks++) {
        float4 a0 = *(const float4*)(fp + ks * 32);
        float4 a1 = *(const float4*)(fp + ks * 32 + 4);
        f16x8 af;
        af[0] = (f16_t)a0.x; af[1] = (f16_t)a0.y; af[2] = (f16_t)a0.z; af[3] = (f16_t)a0.w;
        af[4] = (f16_t)a1.x; af[5] = (f16_t)a1.y; af[6] = (f16_t)a1.z; af[7] = (f16_t)a1.w;
        *(f16x8*)(fb + ks * 32) = af;
        f16x8 bf;
#pragma unroll
        for (int q = 0; q < 8; q++) bf[q] = (f16_t)0;
        if (lo < 4) {
            float4 b0 = *(const float4*)(wsel + ks * 32 + hi * 8);
            float4 b1 = *(const float4*)(wsel + ks * 32 + hi * 8 + 4);
            bf[0] = (f16_t)b0.x; bf[1] = (f16_t)b0.y; bf[2] = (f16_t)b0.z; bf[3] = (f16_t)b0.w;
            bf[4] = (f16_t)b1.x; bf[5] = (f16_t)b1.y; bf[6] = (f16_t)b1.z; bf[7] = (f16_t)b1.w;
        }
        acc = __builtin_amdgcn_mfma_f32_16x16x32_f16(af, bf, acc, 0, 0, 0);
    }
    // C layout: col = lane&15, row_local = (lane>>4)*4 + j
    if (lo < 4) {
        float* oarr = (lo == 0) ? elu : (lo == 1) ? eru : (lo == 2) ? elr : err_;
#pragma unroll
        for (int j = 0; j < 4; j++) {
            int r = base + hi * 4 + j;
            if (r < n) oarr[r] = acc[j];
        }
    }
}

// ---------------- CSR scans ----------------

__global__ __launch_bounds__(256) void scan_block_sum(const int* __restrict__ cnt,
                                                      int* __restrict__ bsum, int n) {
    __shared__ int lds[256];
    int i = blockIdx.x * 256 + threadIdx.x;
    lds[threadIdx.x] = (i < n) ? cnt[i] : 0;
    __syncthreads();
    for (int off = 128; off > 0; off >>= 1) {
        if (threadIdx.x < off) lds[threadIdx.x] += lds[threadIdx.x + off];
        __syncthreads();
    }
    if (threadIdx.x == 0) bsum[blockIdx.x] = lds[0];
}

__global__ __launch_bounds__(1024) void scan_bsum(int* __restrict__ bsum, int nb) {
    __shared__ int lds[1024];
    int t = threadIdx.x;
    int v = (t < nb) ? bsum[t] : 0;
    lds[t] = v;
    __syncthreads();
    for (int off = 1; off < 1024; off <<= 1) {
        int add = (t >= off) ? lds[t - off] : 0;
        __syncthreads();
        lds[t] += add;
        __syncthreads();
    }
    if (t < nb) bsum[t] = lds[t] - v;  // exclusive
}

__global__ __launch_bounds__(256) void scan_final(const int* __restrict__ cnt,
                                                  const int* __restrict__ bsum,
                                                  int* __restrict__ row_ptr,
                                                  int n, int E) {
    __shared__ int lds[256];
    int i = blockIdx.x * 256 + threadIdx.x;
    int v = (i < n) ? cnt[i] : 0;
    lds[threadIdx.x] = v;
    __syncthreads();
    for (int off = 1; off < 256; off <<= 1) {
        int add = (threadIdx.x >= off) ? lds[threadIdx.x - off] : 0;
        __syncthreads();
        lds[threadIdx.x] += add;
        __syncthreads();
    }
    if (i < n) row_ptr[i] = bsum[blockIdx.x] + lds[threadIdx.x] - v;
    if (i == 0) row_ptr[n] = E;
}

// ---------------- atomic-free scatter using precomputed ranks ----------------
// single streaming pass: csr[rp[bin] + rank[e]] = src[e]

__global__ __launch_bounds__(256) void scatter_rank(
    const int* __restrict__ src_u, const int* __restrict__ dst_u,
    const int* __restrict__ src_r, const int* __restrict__ dst_r,
    const unsigned short* __restrict__ rank,
    const int* __restrict__ rp, int* __restrict__ csr,
    int Eu, int Et, int N)
{
    int stride = (int)gridDim.x * 256;
    for (int e = blockIdx.x * 256 + (int)threadIdx.x; e < Et; e += stride) {
        bool fu = (e < Eu);
        int el = fu ? e : e - Eu;
        int d = fu ? dst_u[el] : dst_r[el];
        int bin = fu ? d : N + d;
        int s = fu ? src_u[el] : src_r[el];
        csr[rp[bin] + (int)rank[e]] = s;
    }
}

// ---------------- fused softmax + aggregate, both types interleaved ----------------
// one wave per node; 4 groups of 16 lanes, one edge per group per type in flight.

__global__ __launch_bounds__(256) void aggregate_fused(
    const f16_t* __restrict__ featb,
    const float* __restrict__ elu, const float* __restrict__ eru,
    const float* __restrict__ elr, const float* __restrict__ err_,
    const int* __restrict__ rp, const int* __restrict__ csr,
    f16_t* __restrict__ aggu, f16_t* __restrict__ aggr, int n)
{
    int wid = (int)(((size_t)blockIdx.x * 256 + threadIdx.x) >> 6);
    if (wid >= n) return;
    int lane = threadIdx.x & 63;
    int g = lane >> 4, lo = lane & 15;

    int begu = rp[wid],     endu = rp[wid + 1];
    int begr = rp[n + wid], endr = rp[n + wid + 1];
    float ervu = eru[wid];
    float ervr = err_[wid];

    union UP { f16x2 h; int i; };
    union UV { f16x8 v; f16x2 p[4]; };

    f16x2 z = {(f16_t)0, (f16_t)0};
    f16x2 au0 = z, au1 = z, au2 = z, au3 = z;
    f16x2 ar0 = z, ar1 = z, ar2 = z, ar3 = z;
    float du = 0.f, dr = 0.f;

    int iu = begu + g, ir = begr + g;
    int su = (iu < endu) ? csr[iu] : 0;
    int sr = (ir < endr) ? csr[ir] : 0;

    while (iu < endu || ir < endr) {
        int su2 = (iu + 4 < endu) ? csr[iu + 4] : 0;
        int sr2 = (ir + 4 < endr) ? csr[ir + 4] : 0;
        if (iu < endu) {
            float e = elu[su] + ervu;
            e = fmaxf(e, NEG_SLOPE * e);
            float ex = __expf(e);
            f16_t exh = (f16_t)ex;
            f16x2 exv = {exh, exh};
            UV hc; hc.v = *(const f16x8*)&featb[(size_t)su * F + lo * 8];
            au0 += exv * hc.p[0];
            au1 += exv * hc.p[1];
            au2 += exv * hc.p[2];
            au3 += exv * hc.p[3];
            du += ex;
        }
        if (ir < endr) {
            float e = elr[sr] + ervr;
            e = fmaxf(e, NEG_SLOPE * e);
            float ex = __expf(e);
            f16_t exh = (f16_t)ex;
            f16x2 exv = {exh, exh};
            UV hc; hc.v = *(const f16x8*)&featb[(size_t)sr * F + lo * 8];
            ar0 += exv * hc.p[0];
            ar1 += exv * hc.p[1];
            ar2 += exv * hc.p[2];
            ar3 += exv * hc.p[3];
            dr += ex;
        }
        iu += 4; ir += 4; su = su2; sr = sr2;
    }

#pragma unroll
    for (int off = 16; off < 64; off <<= 1) {
        du += __shfl_xor(du, off);
        dr += __shfl_xor(dr, off);
        UP x;
        x.h = au0; x.i = __shfl_xor(x.i, off); au0 += x.h;
        x.h = au1; x.i = __shfl_xor(x.i, off); au1 += x.h;
        x.h = au2; x.i = __shfl_xor(x.i, off); au2 += x.h;
        x.h = au3; x.i = __shfl_xor(x.i, off); au3 += x.h;
        x.h = ar0; x.i = __shfl_xor(x.i, off); ar0 += x.h;
        x.h = ar1; x.i = __shfl_xor(x.i, off); ar1 += x.h;
        x.h = ar2; x.i = __shfl_xor(x.i, off); ar2 += x.h;
        x.h = ar3; x.i = __shfl_xor(x.i, off); ar3 += x.h;
    }

    if (g == 0) {
        float invu = (du > 0.f) ? 0.5f / du : 0.f;
        float invr = (dr > 0.f) ? 0.5f / dr : 0.f;
        f16_t ihu = (f16_t)invu, ihr = (f16_t)invr;
        f16x2 ivu = {ihu, ihu}, ivr = {ihr, ihr};
        UV ou, orr;
        ou.p[0] = au0 * ivu; ou.p[1] = au1 * ivu; ou.p[2] = au2 * ivu; ou.p[3] = au3 * ivu;
        orr.p[0] = ar0 * ivr; orr.p[1] = ar1 * ivr; orr.p[2] = ar2 * ivr; orr.p[3] = ar3 * ivr;
        *(f16x8*)&aggu[(size_t)wid * F + lo * 8] = ou.v;
        *(f16x8*)&aggr[(size_t)wid * F + lo * 8] = orr.v;
    }
}

// ---------------- final: out = featb@Wts + aggu@Mtu + aggr@Mtr + bn + bias ----------------
// persistent: grid=256, 1024 threads = 16 waves, 256 rows/tile, LDS staged once.

__global__ __launch_bounds__(1024) void mfma_final3(
    const f16_t* __restrict__ featb,
    const f16_t* __restrict__ aggu, const f16_t* __restrict__ aggr,
    const f16_t* __restrict__ Wts, const f16_t* __restrict__ Mtu,
    const f16_t* __restrict__ Mtr,
    const float* __restrict__ bn, const float* __restrict__ bias,
    float* __restrict__ out, int n, int ntiles)
{
    __shared__ f16_t Ls[F * F];
    __shared__ f16_t Lu[F * F];
    __shared__ f16_t Lr[F * F];
    for (int i = threadIdx.x; i < 2048; i += 1024) {
        int c = i >> 4, kc = i & 15, kcs = kc ^ (c & 15);
        *(f16x8*)&Ls[c * F + kcs * 8] = *(const f16x8*)&Wts[c * F + kc * 8];
        *(f16x8*)&Lu[c * F + kcs * 8] = *(const f16x8*)&Mtu[c * F + kc * 8];
        *(f16x8*)&Lr[c * F + kcs * 8] = *(const f16x8*)&Mtr[c * F + kc * 8];
    }
    __syncthreads();

    int lane = threadIdx.x & 63;
    int wave = threadIdx.x >> 6;
    int lo = lane & 15, hi = lane >> 4;

    float cb[8];
#pragma unroll
    for (int t = 0; t < 8; t++) cb[t] = bn[t * 16 + lo] + bias[t * 16 + lo];

    for (int tile = blockIdx.x; tile < ntiles; tile += 256) {
        int row0 = tile * 256 + wave * 16;
        if (row0 >= n) continue;
        int arow = row0 + lo;
        if (arow > n - 1) arow = n - 1;
        const f16_t* pf = featb + (size_t)arow * F + hi * 8;
        const f16_t* pu = aggu + (size_t)arow * F + hi * 8;
        const f16_t* pr = aggr + (size_t)arow * F + hi * 8;

        f32x4 acc[8];
#pragma unroll
        for (int t = 0; t < 8; t++) acc[t] = (f32x4){0.f, 0.f, 0.f, 0.f};

#pragma unroll
        for (int ks = 0; ks < 4; ks++) {
            f16x8 a1 = *(const f16x8*)(pf + ks * 32);
            f16x8 a2 = *(const f16x8*)(pu + ks * 32);
            f16x8 a3 = *(const f16x8*)(pr + ks * 32);
#pragma unroll
            for (int t = 0; t < 8; t++) {
                int c = t * 16 + lo;
                int kcs = (ks * 4 + hi) ^ lo;
                f16x8 bs = *(const f16x8*)&Ls[c * F + kcs * 8];
                f16x8 bu = *(const f16x8*)&Lu[c * F + kcs * 8];
                f16x8 br = *(const f16x8*)&Lr[c * F + kcs * 8];
                acc[t] = __builtin_amdgcn_mfma_f32_16x16x32_f16(a1, bs, acc[t], 0, 0, 0);
                acc[t] = __builtin_amdgcn_mfma_f32_16x16x32_f16(a2, bu, acc[t], 0, 0, 0);
                acc[t] = __builtin_amdgcn_mfma_f32_16x16x32_f16(a3, br, acc[t], 0, 0, 0);
            }
        }

#pragma unroll
        for (int j = 0; j < 4; j++) {
            int r = row0 + hi * 4 + j;
            if (r < n) {
                float* op = out + (size_t)r * F + lo;
#pragma unroll
                for (int t = 0; t < 8; t++) op[t * 16] = acc[t][j] + cb[t];
            }
        }
    }
}

// ---------------- launch ----------------

extern "C" void kernel_launch(void* const* d_in, const int* in_sizes, int n_in,
                              void* d_out, int out_size, void* d_ws, size_t ws_size,
                              hipStream_t stream) {
    const float* feat   = (const float*)d_in[0];
    const int*   src_u  = (const int*)d_in[1];
    const int*   dst_u  = (const int*)d_in[2];
    const int*   src_r  = (const int*)d_in[3];
    const int*   dst_r  = (const int*)d_in[4];
    const float* W_self = (const float*)d_in[5];
    const float* W_u    = (const float*)d_in[6];
    const float* a_l_u  = (const float*)d_in[7];
    const float* a_r_u  = (const float*)d_in[8];
    const float* W_r    = (const float*)d_in[9];
    const float* a_l_r  = (const float*)d_in[10];
    const float* a_r_r  = (const float*)d_in[11];
    const float* W_ngh  = (const float*)d_in[12];
    const float* b_ngh  = (const float*)d_in[13];
    const float* bias   = (const float*)d_in[14];
    float* out = (float*)d_out;

    const int N  = in_sizes[0] / F;
    const int Eu = in_sizes[1];
    const int Er = in_sizes[3];
    const int Et = Eu + Er;

    char* ws = (char*)d_ws;
    size_t off = 0;
    auto alloc = [&](size_t bytes) -> void* {
        void* p = ws + off;
        off = (off + bytes + 255) & ~(size_t)255;
        return p;
    };
    f16_t* featb = (f16_t*)alloc((size_t)N * F * 2);
    f16_t* aggu  = (f16_t*)alloc((size_t)N * F * 2);
    f16_t* aggr  = (f16_t*)alloc((size_t)N * F * 2);
    f16_t* Mt_u  = (f16_t*)alloc((size_t)F * F * 2);
    f16_t* Mt_r  = (f16_t*)alloc((size_t)F * F * 2);
    f16_t* Wt_s  = (f16_t*)alloc((size_t)F * F * 2);
    float* wlu = (float*)alloc((size_t)F * 4);
    float* wru = (float*)alloc((size_t)F * 4);
    float* wlr = (float*)alloc((size_t)F * 4);
    float* wrr = (float*)alloc((size_t)F * 4);
    float* elu = (float*)alloc((size_t)N * 4);
    float* eru = (float*)alloc((size_t)N * 4);
    float* elr = (float*)alloc((size_t)N * 4);
    float* err_ = (float*)alloc((size_t)N * 4);
    int* cnt2 = (int*)alloc((size_t)2 * N * 4);
    int* rp2  = (int*)alloc(((size_t)2 * N + 1) * 4);
    unsigned short* rank = (unsigned short*)alloc((size_t)Et * 2);
    int* csr2 = (int*)alloc((size_t)Et * 4);
    int nbl2 = (2 * N + 255) / 256;
    int* bsum = (int*)alloc((size_t)nbl2 * 4);

    // prep: 256 M-blocks + 128 Wts + 4 wvec + cnt2 zero blocks
    int zb = (N / 2 + 127) / 128;
    prep_mats<<<388 + zb, 128, 0, stream>>>(W_u, W_r, W_self, W_ngh,
                                            a_l_u, a_r_u, a_l_r, a_r_r,
                                            Mt_u, Mt_r, Wt_s, wlu, wru, wlr, wrr,
                                            cnt2, N);

    // interleaved count (8 blocks) / cast (8 blocks) per 16-block group.
    // count needs 256 groups x 8 parts; cast needs castBlocks slots.
    const int G = 256;
    const int chunk = (Et + G - 1) / G;
    int castBlocks = (N + 63) / 64;
    int castGroups = (castBlocks + 7) / 8;
    int groups = (castGroups > G) ? castGroups : G;
    cast_count<<<groups * 16, 256, 0, stream>>>(
        feat, wlu, wru, wlr, wrr, featb, elu, eru, elr, err_,
        dst_u, dst_r, cnt2, rank, Eu, Et, N, chunk, N);

    scan_block_sum<<<nbl2, 256, 0, stream>>>(cnt2, bsum, 2 * N);
    scan_bsum<<<1, 1024, 0, stream>>>(bsum, nbl2);
    scan_final<<<nbl2, 256, 0, stream>>>(cnt2, bsum, rp2, 2 * N, Et);
    scatter_rank<<<2048, 256, 0, stream>>>(src_u, dst_u, src_r, dst_r, rank,
                                           rp2, csr2, Eu, Et, N);

    aggregate_fused<<<(N + 3) / 4, 256, 0, stream>>>(featb, elu, eru, elr, err_,
                                                     rp2, csr2, aggu, aggr, N);
    int ntiles = (N + 255) / 256;
    mfma_final3<<<256, 1024, 0, stream>>>(featb, aggu, aggr,
                                          Wt_s, Mt_u, Mt_r,
                                          b_ngh, bias, out, N, ntiles);
}

// Round 2
// 156.283 us; speedup vs baseline: 1.6310x; 1.3134x over previous
//
#include <hip/hip_runtime.h>

#define F 128
#define NEG_SLOPE 0.2f
#define SHIFT 9
#define BPB 512          // bins per bucket = 1<<SHIFT
#define NBS 512          // max buckets / cnt_bb stride

typedef _Float16 f16_t;
typedef _Float16 f16x8 __attribute__((ext_vector_type(8)));
typedef _Float16 f16x2 __attribute__((ext_vector_type(2)));
typedef float f32x4 __attribute__((ext_vector_type(4)));

// ---------------- prep: composite matrices + projection vectors ----------------
__global__ __launch_bounds__(128) void prep_mats(
    const float* __restrict__ Wu, const float* __restrict__ Wr,
    const float* __restrict__ Ws, const float* __restrict__ Wn,
    const float* __restrict__ alu, const float* __restrict__ aru,
    const float* __restrict__ alr, const float* __restrict__ arr_,
    f16_t* __restrict__ Mtu, f16_t* __restrict__ Mtr, f16_t* __restrict__ Wts,
    float* __restrict__ wlu, float* __restrict__ wru,
    float* __restrict__ wlr, float* __restrict__ wrr)
{
    int b = blockIdx.x;
    int tid = threadIdx.x;
    if (b < 256) {
        int k = b & 127;
        const float* W = (b < 128) ? Wu : Wr;
        f16_t* M = (b < 128) ? Mtu : Mtr;
        float acc = 0.f;
        for (int t = 0; t < F; t++) acc += W[k * F + t] * Wn[t * F + tid];
        M[tid * F + k] = (f16_t)acc;
    } else if (b < 384) {
        int c = b - 256;
        Wts[c * F + tid] = (f16_t)Ws[tid * F + c];
    } else {
        int which = b - 384;
        const float* W = (which < 2) ? Wu : Wr;
        const float* a = (which == 0) ? alu : (which == 1) ? aru : (which == 2) ? alr : arr_;
        float acc = 0.f;
        for (int c = 0; c < F; c++) acc += W[tid * F + c] * a[c];
        float* o = (which == 0) ? wlu : (which == 1) ? wru : (which == 2) ? wlr : wrr;
        o[tid] = acc;
    }
}

// ---------------- cast + el/er (MFMA) merged with p1a bucket histogram ----------------
// blocks [0,256): p1a — per-block LDS histogram of edge buckets -> cnt_bb[block][bucket]
// blocks [256,..): cast — feat f32->f16 + el/er projections, 16 rows/wave via MFMA

__global__ __launch_bounds__(256) void cast_p1a(
    const float* __restrict__ feat,
    const float* __restrict__ wlu, const float* __restrict__ wru,
    const float* __restrict__ wlr, const float* __restrict__ wrr,
    f16_t* __restrict__ featb,
    float* __restrict__ elu, float* __restrict__ eru,
    float* __restrict__ elr, float* __restrict__ err_,
    const int* __restrict__ dst_u, const int* __restrict__ dst_r,
    int* __restrict__ cnt_bb,
    int Eu, int Et, int N, int chunk, int n, int nbk)
{
    int b = blockIdx.x;
    int tid = threadIdx.x;
    if (b < 256) {
        __shared__ int hist[NBS];
        for (int i = tid; i < NBS; i += 256) hist[i] = 0;
        __syncthreads();
        int e0 = b * chunk;
        int e1 = e0 + chunk; if (e1 > Et) e1 = Et;
        int u1 = (e1 < Eu) ? e1 : Eu;
        for (int e = e0 + tid; e < u1; e += 256) {
            int bin = dst_u[e];
            atomicAdd(&hist[bin >> SHIFT], 1);
        }
        int r0 = (e0 > Eu) ? e0 : Eu;
        for (int e = r0 + tid; e < e1; e += 256) {
            int bin = N + dst_r[e - Eu];
            atomicAdd(&hist[bin >> SHIFT], 1);
        }
        __syncthreads();
        for (int i = tid; i < NBS; i += 256) cnt_bb[b * NBS + i] = hist[i];
        return;
    }
    // ---- cast + el/er via MFMA: wave handles 16 rows ----
    int fid = b - 256;
    int lane = tid & 63;
    int wave = tid >> 6;
    int lo = lane & 15, hi = lane >> 4;
    int base = fid * 64 + wave * 16;
    if (base >= n) return;
    int row = base + lo;
    if (row > n - 1) row = n - 1;
    const float* fp = feat + (size_t)row * F + hi * 8;
    f16_t* fb = featb + (size_t)row * F + hi * 8;
    const float* wsel = (lo == 0) ? wlu : (lo == 1) ? wru : (lo == 2) ? wlr : wrr;

    f32x4 acc = (f32x4){0.f, 0.f, 0.f, 0.f};
#pragma unroll
    for (int ks = 0; ks < 4; ks++) {
        float4 a0 = *(const float4*)(fp + ks * 32);
        float4 a1 = *(const float4*)(fp + ks * 32 + 4);
        f16x8 af;
        af[0] = (f16_t)a0.x; af[1] = (f16_t)a0.y; af[2] = (f16_t)a0.z; af[3] = (f16_t)a0.w;
        af[4] = (f16_t)a1.x; af[5] = (f16_t)a1.y; af[6] = (f16_t)a1.z; af[7] = (f16_t)a1.w;
        *(f16x8*)(fb + ks * 32) = af;
        f16x8 bf;
#pragma unroll
        for (int q = 0; q < 8; q++) bf[q] = (f16_t)0;
        if (lo < 4) {
            float4 b0 = *(const float4*)(wsel + ks * 32 + hi * 8);
            float4 b1 = *(const float4*)(wsel + ks * 32 + hi * 8 + 4);
            bf[0] = (f16_t)b0.x; bf[1] = (f16_t)b0.y; bf[2] = (f16_t)b0.z; bf[3] = (f16_t)b0.w;
            bf[4] = (f16_t)b1.x; bf[5] = (f16_t)b1.y; bf[6] = (f16_t)b1.z; bf[7] = (f16_t)b1.w;
        }
        acc = __builtin_amdgcn_mfma_f32_16x16x32_f16(af, bf, acc, 0, 0, 0);
    }
    if (lo < 4) {
        float* oarr = (lo == 0) ? elu : (lo == 1) ? eru : (lo == 2) ? elr : err_;
#pragma unroll
        for (int j = 0; j < 4; j++) {
            int r = base + hi * 4 + j;
            if (r < n) oarr[r] = acc[j];
        }
    }
}

// ---------------- scan per-bucket over blocks ----------------
// one block per bucket: exclusive-scan the 256 per-block counts, emit bucket total.

__global__ __launch_bounds__(256) void scan_bb1(int* __restrict__ cnt_bb,
                                                int* __restrict__ btot, int nbk)
{
    int k = blockIdx.x;
    int tid = threadIdx.x;
    __shared__ int lds[256];
    int v = cnt_bb[tid * NBS + k];
    lds[tid] = v;
    __syncthreads();
    for (int off = 1; off < 256; off <<= 1) {
        int add = (tid >= off) ? lds[tid - off] : 0;
        __syncthreads();
        lds[tid] += add;
        __syncthreads();
    }
    cnt_bb[tid * NBS + k] = lds[tid] - v;   // exclusive, relative within bucket
    if (tid == 255) btot[k] = lds[255];
}

// ---------------- scan bucket totals -> bucket_base; also rp[2N]=Et ----------------

__global__ __launch_bounds__(512) void scan_bb2(const int* __restrict__ btot,
                                                int* __restrict__ bbase,
                                                int* __restrict__ rp,
                                                int nbk, int twoN, int Et)
{
    __shared__ int lds[512];
    int t = threadIdx.x;
    int v = (t < nbk) ? btot[t] : 0;
    lds[t] = v;
    __syncthreads();
    for (int off = 1; off < 512; off <<= 1) {
        int add = (t >= off) ? lds[t - off] : 0;
        __syncthreads();
        lds[t] += add;
        __syncthreads();
    }
    bbase[t] = lds[t] - v;   // exclusive; for t>=nbk this equals total = Et
    if (t == 0) rp[twoN] = Et;
}

// ---------------- p1b: scatter edges into bucket-sorted order (LDS cursors) ----------------

__global__ __launch_bounds__(256) void p1b_scatter(
    const int* __restrict__ src_u, const int* __restrict__ dst_u,
    const int* __restrict__ src_r, const int* __restrict__ dst_r,
    const int* __restrict__ cnt_bb, const int* __restrict__ bbase,
    uint2* __restrict__ bucketed,
    int Eu, int Et, int N, int chunk, int nbk)
{
    int b = blockIdx.x;
    int tid = threadIdx.x;
    __shared__ int cur[NBS];
    for (int i = tid; i < nbk; i += 256) cur[i] = bbase[i] + cnt_bb[b * NBS + i];
    __syncthreads();
    int e0 = b * chunk;
    int e1 = e0 + chunk; if (e1 > Et) e1 = Et;
    int u1 = (e1 < Eu) ? e1 : Eu;
    for (int e = e0 + tid; e < u1; e += 256) {
        int bin = dst_u[e];
        int s = src_u[e];
        int pos = atomicAdd(&cur[bin >> SHIFT], 1);
        bucketed[pos] = make_uint2((unsigned)s, (unsigned)bin);
    }
    int r0 = (e0 > Eu) ? e0 : Eu;
    for (int e = r0 + tid; e < e1; e += 256) {
        int bin = N + dst_r[e - Eu];
        int s = src_r[e - Eu];
        int pos = atomicAdd(&cur[bin >> SHIFT], 1);
        bucketed[pos] = make_uint2((unsigned)s, (unsigned)bin);
    }
}

// ---------------- p2: per-bucket fine CSR build (LDS hist + scan + scatter) ----------------

__global__ __launch_bounds__(256) void p2_build(
    const uint2* __restrict__ bucketed, const int* __restrict__ bbase,
    int* __restrict__ rp, int* __restrict__ csr, int twoN)
{
    int k = blockIdx.x;
    int tid = threadIdx.x;
    int beg = bbase[k], end = bbase[k + 1];
    __shared__ int hist[BPB];
    __shared__ int psum[256];
    for (int i = tid; i < BPB; i += 256) hist[i] = 0;
    __syncthreads();
    for (int i = beg + tid; i < end; i += 256) {
        uint2 p = bucketed[i];
        atomicAdd(&hist[p.y & (BPB - 1)], 1);
    }
    __syncthreads();
    int a0 = hist[2 * tid], a1 = hist[2 * tid + 1];
    psum[tid] = a0 + a1;
    __syncthreads();
    for (int off = 1; off < 256; off <<= 1) {
        int add = (tid >= off) ? psum[tid - off] : 0;
        __syncthreads();
        psum[tid] += add;
        __syncthreads();
    }
    int base0 = beg + psum[tid] - (a0 + a1);   // exclusive prefix of element 2*tid
    int bin0 = (k << SHIFT) + 2 * tid;
    if (bin0 < twoN)     rp[bin0]     = base0;
    if (bin0 + 1 < twoN) rp[bin0 + 1] = base0 + a0;
    __syncthreads();
    hist[2 * tid]     = base0;        // reuse hist as absolute cursors
    hist[2 * tid + 1] = base0 + a0;
    __syncthreads();
    for (int i = beg + tid; i < end; i += 256) {
        uint2 p = bucketed[i];
        int pos = atomicAdd(&hist[p.y & (BPB - 1)], 1);
        csr[pos] = (int)p.x;
    }
}

// ---------------- fused softmax + aggregate, both types interleaved ----------------

__global__ __launch_bounds__(256) void aggregate_fused(
    const f16_t* __restrict__ featb,
    const float* __restrict__ elu, const float* __restrict__ eru,
    const float* __restrict__ elr, const float* __restrict__ err_,
    const int* __restrict__ rp, const int* __restrict__ csr,
    f16_t* __restrict__ aggu, f16_t* __restrict__ aggr, int n)
{
    int wid = (int)(((size_t)blockIdx.x * 256 + threadIdx.x) >> 6);
    if (wid >= n) return;
    int lane = threadIdx.x & 63;
    int g = lane >> 4, lo = lane & 15;

    int begu = rp[wid],     endu = rp[wid + 1];
    int begr = rp[n + wid], endr = rp[n + wid + 1];
    float ervu = eru[wid];
    float ervr = err_[wid];

    union UP { f16x2 h; int i; };
    union UV { f16x8 v; f16x2 p[4]; };

    f16x2 z = {(f16_t)0, (f16_t)0};
    f16x2 au0 = z, au1 = z, au2 = z, au3 = z;
    f16x2 ar0 = z, ar1 = z, ar2 = z, ar3 = z;
    float du = 0.f, dr = 0.f;

    int iu = begu + g, ir = begr + g;
    int su = (iu < endu) ? csr[iu] : 0;
    int sr = (ir < endr) ? csr[ir] : 0;

    while (iu < endu || ir < endr) {
        int su2 = (iu + 4 < endu) ? csr[iu + 4] : 0;
        int sr2 = (ir + 4 < endr) ? csr[ir + 4] : 0;
        if (iu < endu) {
            float e = elu[su] + ervu;
            e = fmaxf(e, NEG_SLOPE * e);
            float ex = __expf(e);
            f16_t exh = (f16_t)ex;
            f16x2 exv = {exh, exh};
            UV hc; hc.v = *(const f16x8*)&featb[(size_t)su * F + lo * 8];
            au0 += exv * hc.p[0];
            au1 += exv * hc.p[1];
            au2 += exv * hc.p[2];
            au3 += exv * hc.p[3];
            du += ex;
        }
        if (ir < endr) {
            float e = elr[sr] + ervr;
            e = fmaxf(e, NEG_SLOPE * e);
            float ex = __expf(e);
            f16_t exh = (f16_t)ex;
            f16x2 exv = {exh, exh};
            UV hc; hc.v = *(const f16x8*)&featb[(size_t)sr * F + lo * 8];
            ar0 += exv * hc.p[0];
            ar1 += exv * hc.p[1];
            ar2 += exv * hc.p[2];
            ar3 += exv * hc.p[3];
            dr += ex;
        }
        iu += 4; ir += 4; su = su2; sr = sr2;
    }

#pragma unroll
    for (int off = 16; off < 64; off <<= 1) {
        du += __shfl_xor(du, off);
        dr += __shfl_xor(dr, off);
        UP x;
        x.h = au0; x.i = __shfl_xor(x.i, off); au0 += x.h;
        x.h = au1; x.i = __shfl_xor(x.i, off); au1 += x.h;
        x.h = au2; x.i = __shfl_xor(x.i, off); au2 += x.h;
        x.h = au3; x.i = __shfl_xor(x.i, off); au3 += x.h;
        x.h = ar0; x.i = __shfl_xor(x.i, off); ar0 += x.h;
        x.h = ar1; x.i = __shfl_xor(x.i, off); ar1 += x.h;
        x.h = ar2; x.i = __shfl_xor(x.i, off); ar2 += x.h;
        x.h = ar3; x.i = __shfl_xor(x.i, off); ar3 += x.h;
    }

    if (g == 0) {
        float invu = (du > 0.f) ? 0.5f / du : 0.f;
        float invr = (dr > 0.f) ? 0.5f / dr : 0.f;
        f16_t ihu = (f16_t)invu, ihr = (f16_t)invr;
        f16x2 ivu = {ihu, ihu}, ivr = {ihr, ihr};
        UV ou, orr;
        ou.p[0] = au0 * ivu; ou.p[1] = au1 * ivu; ou.p[2] = au2 * ivu; ou.p[3] = au3 * ivu;
        orr.p[0] = ar0 * ivr; orr.p[1] = ar1 * ivr; orr.p[2] = ar2 * ivr; orr.p[3] = ar3 * ivr;
        *(f16x8*)&aggu[(size_t)wid * F + lo * 8] = ou.v;
        *(f16x8*)&aggr[(size_t)wid * F + lo * 8] = orr.v;
    }
}

// ---------------- final: out = featb@Wts + aggu@Mtu + aggr@Mtr + bn + bias ----------------

__global__ __launch_bounds__(1024) void mfma_final3(
    const f16_t* __restrict__ featb,
    const f16_t* __restrict__ aggu, const f16_t* __restrict__ aggr,
    const f16_t* __restrict__ Wts, const f16_t* __restrict__ Mtu,
    const f16_t* __restrict__ Mtr,
    const float* __restrict__ bn, const float* __restrict__ bias,
    float* __restrict__ out, int n, int ntiles)
{
    __shared__ f16_t Ls[F * F];
    __shared__ f16_t Lu[F * F];
    __shared__ f16_t Lr[F * F];
    for (int i = threadIdx.x; i < 2048; i += 1024) {
        int c = i >> 4, kc = i & 15, kcs = kc ^ (c & 15);
        *(f16x8*)&Ls[c * F + kcs * 8] = *(const f16x8*)&Wts[c * F + kc * 8];
        *(f16x8*)&Lu[c * F + kcs * 8] = *(const f16x8*)&Mtu[c * F + kc * 8];
        *(f16x8*)&Lr[c * F + kcs * 8] = *(const f16x8*)&Mtr[c * F + kc * 8];
    }
    __syncthreads();

    int lane = threadIdx.x & 63;
    int wave = threadIdx.x >> 6;
    int lo = lane & 15, hi = lane >> 4;

    float cb[8];
#pragma unroll
    for (int t = 0; t < 8; t++) cb[t] = bn[t * 16 + lo] + bias[t * 16 + lo];

    for (int tile = blockIdx.x; tile < ntiles; tile += 256) {
        int row0 = tile * 256 + wave * 16;
        if (row0 >= n) continue;
        int arow = row0 + lo;
        if (arow > n - 1) arow = n - 1;
        const f16_t* pf = featb + (size_t)arow * F + hi * 8;
        const f16_t* pu = aggu + (size_t)arow * F + hi * 8;
        const f16_t* pr = aggr + (size_t)arow * F + hi * 8;

        f32x4 acc[8];
#pragma unroll
        for (int t = 0; t < 8; t++) acc[t] = (f32x4){0.f, 0.f, 0.f, 0.f};

#pragma unroll
        for (int ks = 0; ks < 4; ks++) {
            f16x8 a1 = *(const f16x8*)(pf + ks * 32);
            f16x8 a2 = *(const f16x8*)(pu + ks * 32);
            f16x8 a3 = *(const f16x8*)(pr + ks * 32);
#pragma unroll
            for (int t = 0; t < 8; t++) {
                int c = t * 16 + lo;
                int kcs = (ks * 4 + hi) ^ lo;
                f16x8 bs = *(const f16x8*)&Ls[c * F + kcs * 8];
                f16x8 bu = *(const f16x8*)&Lu[c * F + kcs * 8];
                f16x8 br = *(const f16x8*)&Lr[c * F + kcs * 8];
                acc[t] = __builtin_amdgcn_mfma_f32_16x16x32_f16(a1, bs, acc[t], 0, 0, 0);
                acc[t] = __builtin_amdgcn_mfma_f32_16x16x32_f16(a2, bu, acc[t], 0, 0, 0);
                acc[t] = __builtin_amdgcn_mfma_f32_16x16x32_f16(a3, br, acc[t], 0, 0, 0);
            }
        }

#pragma unroll
        for (int j = 0; j < 4; j++) {
            int r = row0 + hi * 4 + j;
            if (r < n) {
                float* op = out + (size_t)r * F + lo;
#pragma unroll
                for (int t = 0; t < 8; t++) op[t * 16] = acc[t][j] + cb[t];
            }
        }
    }
}

// ---------------- launch ----------------

extern "C" void kernel_launch(void* const* d_in, const int* in_sizes, int n_in,
                              void* d_out, int out_size, void* d_ws, size_t ws_size,
                              hipStream_t stream) {
    const float* feat   = (const float*)d_in[0];
    const int*   src_u  = (const int*)d_in[1];
    const int*   dst_u  = (const int*)d_in[2];
    const int*   src_r  = (const int*)d_in[3];
    const int*   dst_r  = (const int*)d_in[4];
    const float* W_self = (const float*)d_in[5];
    const float* W_u    = (const float*)d_in[6];
    const float* a_l_u  = (const float*)d_in[7];
    const float* a_r_u  = (const float*)d_in[8];
    const float* W_r    = (const float*)d_in[9];
    const float* a_l_r  = (const float*)d_in[10];
    const float* a_r_r  = (const float*)d_in[11];
    const float* W_ngh  = (const float*)d_in[12];
    const float* b_ngh  = (const float*)d_in[13];
    const float* bias   = (const float*)d_in[14];
    float* out = (float*)d_out;

    const int N  = in_sizes[0] / F;
    const int Eu = in_sizes[1];
    const int Er = in_sizes[3];
    const int Et = Eu + Er;
    const int twoN = 2 * N;
    const int nbk = (twoN + BPB - 1) >> SHIFT;   // buckets (<= NBS)

    char* ws = (char*)d_ws;
    size_t off = 0;
    auto alloc = [&](size_t bytes) -> void* {
        void* p = ws + off;
        off = (off + bytes + 255) & ~(size_t)255;
        return p;
    };
    f16_t* featb = (f16_t*)alloc((size_t)N * F * 2);
    f16_t* aggu  = (f16_t*)alloc((size_t)N * F * 2);
    f16_t* aggr  = (f16_t*)alloc((size_t)N * F * 2);
    f16_t* Mt_u  = (f16_t*)alloc((size_t)F * F * 2);
    f16_t* Mt_r  = (f16_t*)alloc((size_t)F * F * 2);
    f16_t* Wt_s  = (f16_t*)alloc((size_t)F * F * 2);
    float* wlu = (float*)alloc((size_t)F * 4);
    float* wru = (float*)alloc((size_t)F * 4);
    float* wlr = (float*)alloc((size_t)F * 4);
    float* wrr = (float*)alloc((size_t)F * 4);
    float* elu = (float*)alloc((size_t)N * 4);
    float* eru = (float*)alloc((size_t)N * 4);
    float* elr = (float*)alloc((size_t)N * 4);
    float* err_ = (float*)alloc((size_t)N * 4);
    int* cnt_bb = (int*)alloc((size_t)256 * NBS * 4);
    int* btot   = (int*)alloc((size_t)NBS * 4);
    int* bbase  = (int*)alloc((size_t)(NBS + 1) * 4);
    int* rp2    = (int*)alloc(((size_t)twoN + 1) * 4);
    uint2* bucketed = (uint2*)alloc((size_t)Et * 8);
    int* csr2   = (int*)alloc((size_t)Et * 4);

    prep_mats<<<388, 128, 0, stream>>>(W_u, W_r, W_self, W_ngh,
                                       a_l_u, a_r_u, a_l_r, a_r_r,
                                       Mt_u, Mt_r, Wt_s, wlu, wru, wlr, wrr);

    const int chunk = (Et + 255) / 256;
    int castBlocks = (N + 63) / 64;
    cast_p1a<<<256 + castBlocks, 256, 0, stream>>>(
        feat, wlu, wru, wlr, wrr, featb, elu, eru, elr, err_,
        dst_u, dst_r, cnt_bb, Eu, Et, N, chunk, N, nbk);

    scan_bb1<<<nbk, 256, 0, stream>>>(cnt_bb, btot, nbk);
    scan_bb2<<<1, 512, 0, stream>>>(btot, bbase, rp2, nbk, twoN, Et);
    p1b_scatter<<<256, 256, 0, stream>>>(src_u, dst_u, src_r, dst_r,
                                         cnt_bb, bbase, bucketed,
                                         Eu, Et, N, chunk, nbk);
    p2_build<<<nbk, 256, 0, stream>>>(bucketed, bbase, rp2, csr2, twoN);

    aggregate_fused<<<(N + 3) / 4, 256, 0, stream>>>(featb, elu, eru, elr, err_,
                                                     rp2, csr2, aggu, aggr, N);
    int ntiles = (N + 255) / 256;
    mfma_final3<<<256, 1024, 0, stream>>>(featb, aggu, aggr,
                                          Wt_s, Mt_u, Mt_r,
                                          b_ngh, bias, out, N, ntiles);
}

// Round 3
// 154.096 us; speedup vs baseline: 1.6542x; 1.0142x over previous
//
#include <hip/hip_runtime.h>

#define F 128
#define NEG_SLOPE 0.2f
#define SHIFT 9
#define BPB 512          // bins per bucket = 1<<SHIFT
#define NBS 512          // max buckets / cnt_bb stride

typedef _Float16 f16_t;
typedef _Float16 f16x8 __attribute__((ext_vector_type(8)));
typedef _Float16 f16x2 __attribute__((ext_vector_type(2)));
typedef float f32x4 __attribute__((ext_vector_type(4)));

// ---------------- prep: composite matrices + projection vectors ----------------
__global__ __launch_bounds__(128) void prep_mats(
    const float* __restrict__ Wu, const float* __restrict__ Wr,
    const float* __restrict__ Ws, const float* __restrict__ Wn,
    const float* __restrict__ alu, const float* __restrict__ aru,
    const float* __restrict__ alr, const float* __restrict__ arr_,
    f16_t* __restrict__ Mtu, f16_t* __restrict__ Mtr, f16_t* __restrict__ Wts,
    float* __restrict__ wlu, float* __restrict__ wru,
    float* __restrict__ wlr, float* __restrict__ wrr)
{
    int b = blockIdx.x;
    int tid = threadIdx.x;
    if (b < 256) {
        int k = b & 127;
        const float* W = (b < 128) ? Wu : Wr;
        f16_t* M = (b < 128) ? Mtu : Mtr;
        float acc = 0.f;
        for (int t = 0; t < F; t++) acc += W[k * F + t] * Wn[t * F + tid];
        M[tid * F + k] = (f16_t)acc;
    } else if (b < 384) {
        int c = b - 256;
        Wts[c * F + tid] = (f16_t)Ws[tid * F + c];
    } else {
        int which = b - 384;
        const float* W = (which < 2) ? Wu : Wr;
        const float* a = (which == 0) ? alu : (which == 1) ? aru : (which == 2) ? alr : arr_;
        float acc = 0.f;
        for (int c = 0; c < F; c++) acc += W[tid * F + c] * a[c];
        float* o = (which == 0) ? wlu : (which == 1) ? wru : (which == 2) ? wlr : wrr;
        o[tid] = acc;
    }
}

// ---------------- cast + el/er (MFMA) merged with p1a bucket histogram ----------------

__global__ __launch_bounds__(256) void cast_p1a(
    const float* __restrict__ feat,
    const float* __restrict__ wlu, const float* __restrict__ wru,
    const float* __restrict__ wlr, const float* __restrict__ wrr,
    f16_t* __restrict__ featb,
    float* __restrict__ elu, float* __restrict__ eru,
    float* __restrict__ elr, float* __restrict__ err_,
    const int* __restrict__ dst_u, const int* __restrict__ dst_r,
    int* __restrict__ cnt_bb,
    int Eu, int Et, int N, int chunk, int n, int nbk)
{
    int b = blockIdx.x;
    int tid = threadIdx.x;
    if (b < 256) {
        __shared__ int hist[NBS];
        for (int i = tid; i < NBS; i += 256) hist[i] = 0;
        __syncthreads();
        int e0 = b * chunk;
        int e1 = e0 + chunk; if (e1 > Et) e1 = Et;
        int u1 = (e1 < Eu) ? e1 : Eu;
        for (int e = e0 + tid; e < u1; e += 256) {
            int bin = dst_u[e];
            atomicAdd(&hist[bin >> SHIFT], 1);
        }
        int r0 = (e0 > Eu) ? e0 : Eu;
        for (int e = r0 + tid; e < e1; e += 256) {
            int bin = N + dst_r[e - Eu];
            atomicAdd(&hist[bin >> SHIFT], 1);
        }
        __syncthreads();
        for (int i = tid; i < NBS; i += 256) cnt_bb[b * NBS + i] = hist[i];
        return;
    }
    // ---- cast + el/er via MFMA: wave handles 16 rows ----
    int fid = b - 256;
    int lane = tid & 63;
    int wave = tid >> 6;
    int lo = lane & 15, hi = lane >> 4;
    int base = fid * 64 + wave * 16;
    if (base >= n) return;
    int row = base + lo;
    if (row > n - 1) row = n - 1;
    const float* fp = feat + (size_t)row * F + hi * 8;
    f16_t* fb = featb + (size_t)row * F + hi * 8;
    const float* wsel = (lo == 0) ? wlu : (lo == 1) ? wru : (lo == 2) ? wlr : wrr;

    f32x4 acc = (f32x4){0.f, 0.f, 0.f, 0.f};
#pragma unroll
    for (int ks = 0; ks < 4; ks++) {
        float4 a0 = *(const float4*)(fp + ks * 32);
        float4 a1 = *(const float4*)(fp + ks * 32 + 4);
        f16x8 af;
        af[0] = (f16_t)a0.x; af[1] = (f16_t)a0.y; af[2] = (f16_t)a0.z; af[3] = (f16_t)a0.w;
        af[4] = (f16_t)a1.x; af[5] = (f16_t)a1.y; af[6] = (f16_t)a1.z; af[7] = (f16_t)a1.w;
        *(f16x8*)(fb + ks * 32) = af;
        f16x8 bf;
#pragma unroll
        for (int q = 0; q < 8; q++) bf[q] = (f16_t)0;
        if (lo < 4) {
            float4 b0 = *(const float4*)(wsel + ks * 32 + hi * 8);
            float4 b1 = *(const float4*)(wsel + ks * 32 + hi * 8 + 4);
            bf[0] = (f16_t)b0.x; bf[1] = (f16_t)b0.y; bf[2] = (f16_t)b0.z; bf[3] = (f16_t)b0.w;
            bf[4] = (f16_t)b1.x; bf[5] = (f16_t)b1.y; bf[6] = (f16_t)b1.z; bf[7] = (f16_t)b1.w;
        }
        acc = __builtin_amdgcn_mfma_f32_16x16x32_f16(af, bf, acc, 0, 0, 0);
    }
    if (lo < 4) {
        float* oarr = (lo == 0) ? elu : (lo == 1) ? eru : (lo == 2) ? elr : err_;
#pragma unroll
        for (int j = 0; j < 4; j++) {
            int r = base + hi * 4 + j;
            if (r < n) oarr[r] = acc[j];
        }
    }
}

// ---------------- scan per-bucket over blocks ----------------

__global__ __launch_bounds__(256) void scan_bb1(int* __restrict__ cnt_bb,
                                                int* __restrict__ btot, int nbk)
{
    int k = blockIdx.x;
    int tid = threadIdx.x;
    __shared__ int lds[256];
    int v = cnt_bb[tid * NBS + k];
    lds[tid] = v;
    __syncthreads();
    for (int off = 1; off < 256; off <<= 1) {
        int add = (tid >= off) ? lds[tid - off] : 0;
        __syncthreads();
        lds[tid] += add;
        __syncthreads();
    }
    cnt_bb[tid * NBS + k] = lds[tid] - v;   // exclusive, relative within bucket
    if (tid == 255) btot[k] = lds[255];
}

__global__ __launch_bounds__(512) void scan_bb2(const int* __restrict__ btot,
                                                int* __restrict__ bbase,
                                                int* __restrict__ rp,
                                                int nbk, int twoN, int Et)
{
    __shared__ int lds[512];
    int t = threadIdx.x;
    int v = (t < nbk) ? btot[t] : 0;
    lds[t] = v;
    __syncthreads();
    for (int off = 1; off < 512; off <<= 1) {
        int add = (t >= off) ? lds[t - off] : 0;
        __syncthreads();
        lds[t] += add;
        __syncthreads();
    }
    bbase[t] = lds[t] - v;   // exclusive; for t>=nbk this equals total = Et
    if (t == 0) rp[twoN] = Et;
}

// ---------------- p1b: scatter edges into bucket-sorted order (LDS cursors) ----------------

__global__ __launch_bounds__(256) void p1b_scatter(
    const int* __restrict__ src_u, const int* __restrict__ dst_u,
    const int* __restrict__ src_r, const int* __restrict__ dst_r,
    const int* __restrict__ cnt_bb, const int* __restrict__ bbase,
    uint2* __restrict__ bucketed,
    int Eu, int Et, int N, int chunk, int nbk)
{
    int b = blockIdx.x;
    int tid = threadIdx.x;
    __shared__ int cur[NBS];
    for (int i = tid; i < nbk; i += 256) cur[i] = bbase[i] + cnt_bb[b * NBS + i];
    __syncthreads();
    int e0 = b * chunk;
    int e1 = e0 + chunk; if (e1 > Et) e1 = Et;
    int u1 = (e1 < Eu) ? e1 : Eu;
    for (int e = e0 + tid; e < u1; e += 256) {
        int bin = dst_u[e];
        int s = src_u[e];
        int pos = atomicAdd(&cur[bin >> SHIFT], 1);
        bucketed[pos] = make_uint2((unsigned)s, (unsigned)bin);
    }
    int r0 = (e0 > Eu) ? e0 : Eu;
    for (int e = r0 + tid; e < e1; e += 256) {
        int bin = N + dst_r[e - Eu];
        int s = src_r[e - Eu];
        int pos = atomicAdd(&cur[bin >> SHIFT], 1);
        bucketed[pos] = make_uint2((unsigned)s, (unsigned)bin);
    }
}

// ---------------- p2: per-bucket fine CSR build (LDS hist + scan + scatter) ----------------

__global__ __launch_bounds__(256) void p2_build(
    const uint2* __restrict__ bucketed, const int* __restrict__ bbase,
    int* __restrict__ rp, int* __restrict__ csr, int twoN)
{
    int k = blockIdx.x;
    int tid = threadIdx.x;
    int beg = bbase[k], end = bbase[k + 1];
    __shared__ int hist[BPB];
    __shared__ int psum[256];
    for (int i = tid; i < BPB; i += 256) hist[i] = 0;
    __syncthreads();
    for (int i = beg + tid; i < end; i += 256) {
        uint2 p = bucketed[i];
        atomicAdd(&hist[p.y & (BPB - 1)], 1);
    }
    __syncthreads();
    int a0 = hist[2 * tid], a1 = hist[2 * tid + 1];
    psum[tid] = a0 + a1;
    __syncthreads();
    for (int off = 1; off < 256; off <<= 1) {
        int add = (tid >= off) ? psum[tid - off] : 0;
        __syncthreads();
        psum[tid] += add;
        __syncthreads();
    }
    int base0 = beg + psum[tid] - (a0 + a1);   // exclusive prefix of element 2*tid
    int bin0 = (k << SHIFT) + 2 * tid;
    if (bin0 < twoN)     rp[bin0]     = base0;
    if (bin0 + 1 < twoN) rp[bin0 + 1] = base0 + a0;
    __syncthreads();
    hist[2 * tid]     = base0;        // reuse hist as absolute cursors
    hist[2 * tid + 1] = base0 + a0;
    __syncthreads();
    for (int i = beg + tid; i < end; i += 256) {
        uint2 p = bucketed[i];
        int pos = atomicAdd(&hist[p.y & (BPB - 1)], 1);
        csr[pos] = (int)p.x;
    }
}

// ---------------- fused softmax + aggregate, both types, 2x unroll + row prefetch -------
// one wave per node; 4 groups of 16 lanes; each group: edges (i, i+4) per type, stride 8.
// Pipeline: rows+els for current pair in registers; next pair's loads issued before the
// current pair's FMAs -> 4 independent 256B row gathers in flight per group.

__global__ __launch_bounds__(256) void aggregate_fused(
    const f16_t* __restrict__ featb,
    const float* __restrict__ elu, const float* __restrict__ eru,
    const float* __restrict__ elr, const float* __restrict__ err_,
    const int* __restrict__ rp, const int* __restrict__ csr,
    f16_t* __restrict__ aggu, f16_t* __restrict__ aggr, int n)
{
    int wid = (int)(((size_t)blockIdx.x * 256 + threadIdx.x) >> 6);
    if (wid >= n) return;
    int lane = threadIdx.x & 63;
    int g = lane >> 4, lo = lane & 15;

    int begu = rp[wid],     endu = rp[wid + 1];
    int begr = rp[n + wid], endr = rp[n + wid + 1];
    float ervu = eru[wid];
    float ervr = err_[wid];

    union UP { f16x2 h; int i; };
    union UV { f16x8 v; f16x2 p[4]; };

    f16x2 z = {(f16_t)0, (f16_t)0};
    f16x2 au0 = z, au1 = z, au2 = z, au3 = z;
    f16x2 ar0 = z, ar1 = z, ar2 = z, ar3 = z;
    float du = 0.f, dr = 0.f;

    int iu = begu + g, ir = begr + g;

    // prologue: load current pair state
    int cu0 = (iu     < endu) ? csr[iu]     : -1;
    int cu1 = (iu + 4 < endu) ? csr[iu + 4] : -1;
    int cr0 = (ir     < endr) ? csr[ir]     : -1;
    int cr1 = (ir + 4 < endr) ? csr[ir + 4] : -1;
    UV hu0, hu1, hr0, hr1;
    hu0.v = *(const f16x8*)&featb[(size_t)(cu0 < 0 ? 0 : cu0) * F + lo * 8];
    hu1.v = *(const f16x8*)&featb[(size_t)(cu1 < 0 ? 0 : cu1) * F + lo * 8];
    hr0.v = *(const f16x8*)&featb[(size_t)(cr0 < 0 ? 0 : cr0) * F + lo * 8];
    hr1.v = *(const f16x8*)&featb[(size_t)(cr1 < 0 ? 0 : cr1) * F + lo * 8];
    float eu0 = elu[cu0 < 0 ? 0 : cu0];
    float eu1 = elu[cu1 < 0 ? 0 : cu1];
    float er0 = elr[cr0 < 0 ? 0 : cr0];
    float er1 = elr[cr1 < 0 ? 0 : cr1];

    while (iu < endu || ir < endr) {
        // issue next pair's loads (independent of current compute)
        int nu0 = (iu + 8  < endu) ? csr[iu + 8]  : -1;
        int nu1 = (iu + 12 < endu) ? csr[iu + 12] : -1;
        int nr0 = (ir + 8  < endr) ? csr[ir + 8]  : -1;
        int nr1 = (ir + 12 < endr) ? csr[ir + 12] : -1;
        UV pu0, pu1, pr0, pr1;
        pu0.v = *(const f16x8*)&featb[(size_t)(nu0 < 0 ? 0 : nu0) * F + lo * 8];
        pu1.v = *(const f16x8*)&featb[(size_t)(nu1 < 0 ? 0 : nu1) * F + lo * 8];
        pr0.v = *(const f16x8*)&featb[(size_t)(nr0 < 0 ? 0 : nr0) * F + lo * 8];
        pr1.v = *(const f16x8*)&featb[(size_t)(nr1 < 0 ? 0 : nr1) * F + lo * 8];
        float fu0 = elu[nu0 < 0 ? 0 : nu0];
        float fu1 = elu[nu1 < 0 ? 0 : nu1];
        float fr0 = elr[nr0 < 0 ? 0 : nr0];
        float fr1 = elr[nr1 < 0 ? 0 : nr1];

        // consume current pair (branchless; invalid -> weight 0)
        {
            float e = eu0 + ervu; e = fmaxf(e, NEG_SLOPE * e);
            float ex = (cu0 >= 0) ? __expf(e) : 0.f;
            f16_t exh = (f16_t)ex; f16x2 exv = {exh, exh};
            au0 += exv * hu0.p[0]; au1 += exv * hu0.p[1];
            au2 += exv * hu0.p[2]; au3 += exv * hu0.p[3];
            du += ex;
        }
        {
            float e = eu1 + ervu; e = fmaxf(e, NEG_SLOPE * e);
            float ex = (cu1 >= 0) ? __expf(e) : 0.f;
            f16_t exh = (f16_t)ex; f16x2 exv = {exh, exh};
            au0 += exv * hu1.p[0]; au1 += exv * hu1.p[1];
            au2 += exv * hu1.p[2]; au3 += exv * hu1.p[3];
            du += ex;
        }
        {
            float e = er0 + ervr; e = fmaxf(e, NEG_SLOPE * e);
            float ex = (cr0 >= 0) ? __expf(e) : 0.f;
            f16_t exh = (f16_t)ex; f16x2 exv = {exh, exh};
            ar0 += exv * hr0.p[0]; ar1 += exv * hr0.p[1];
            ar2 += exv * hr0.p[2]; ar3 += exv * hr0.p[3];
            dr += ex;
        }
        {
            float e = er1 + ervr; e = fmaxf(e, NEG_SLOPE * e);
            float ex = (cr1 >= 0) ? __expf(e) : 0.f;
            f16_t exh = (f16_t)ex; f16x2 exv = {exh, exh};
            ar0 += exv * hr1.p[0]; ar1 += exv * hr1.p[1];
            ar2 += exv * hr1.p[2]; ar3 += exv * hr1.p[3];
            dr += ex;
        }

        hu0 = pu0; hu1 = pu1; hr0 = pr0; hr1 = pr1;
        eu0 = fu0; eu1 = fu1; er0 = fr0; er1 = fr1;
        cu0 = nu0; cu1 = nu1; cr0 = nr0; cr1 = nr1;
        iu += 8; ir += 8;
    }

#pragma unroll
    for (int off = 16; off < 64; off <<= 1) {
        du += __shfl_xor(du, off);
        dr += __shfl_xor(dr, off);
        UP x;
        x.h = au0; x.i = __shfl_xor(x.i, off); au0 += x.h;
        x.h = au1; x.i = __shfl_xor(x.i, off); au1 += x.h;
        x.h = au2; x.i = __shfl_xor(x.i, off); au2 += x.h;
        x.h = au3; x.i = __shfl_xor(x.i, off); au3 += x.h;
        x.h = ar0; x.i = __shfl_xor(x.i, off); ar0 += x.h;
        x.h = ar1; x.i = __shfl_xor(x.i, off); ar1 += x.h;
        x.h = ar2; x.i = __shfl_xor(x.i, off); ar2 += x.h;
        x.h = ar3; x.i = __shfl_xor(x.i, off); ar3 += x.h;
    }

    if (g == 0) {
        float invu = (du > 0.f) ? 0.5f / du : 0.f;
        float invr = (dr > 0.f) ? 0.5f / dr : 0.f;
        f16_t ihu = (f16_t)invu, ihr = (f16_t)invr;
        f16x2 ivu = {ihu, ihu}, ivr = {ihr, ihr};
        UV ou, orr;
        ou.p[0] = au0 * ivu; ou.p[1] = au1 * ivu; ou.p[2] = au2 * ivu; ou.p[3] = au3 * ivu;
        orr.p[0] = ar0 * ivr; orr.p[1] = ar1 * ivr; orr.p[2] = ar2 * ivr; orr.p[3] = ar3 * ivr;
        *(f16x8*)&aggu[(size_t)wid * F + lo * 8] = ou.v;
        *(f16x8*)&aggr[(size_t)wid * F + lo * 8] = orr.v;
    }
}

// ---------------- final: out = featb@Wts + aggu@Mtu + aggr@Mtr + bn + bias ----------------

__global__ __launch_bounds__(1024) void mfma_final3(
    const f16_t* __restrict__ featb,
    const f16_t* __restrict__ aggu, const f16_t* __restrict__ aggr,
    const f16_t* __restrict__ Wts, const f16_t* __restrict__ Mtu,
    const f16_t* __restrict__ Mtr,
    const float* __restrict__ bn, const float* __restrict__ bias,
    float* __restrict__ out, int n, int ntiles)
{
    __shared__ f16_t Ls[F * F];
    __shared__ f16_t Lu[F * F];
    __shared__ f16_t Lr[F * F];
    for (int i = threadIdx.x; i < 2048; i += 1024) {
        int c = i >> 4, kc = i & 15, kcs = kc ^ (c & 15);
        *(f16x8*)&Ls[c * F + kcs * 8] = *(const f16x8*)&Wts[c * F + kc * 8];
        *(f16x8*)&Lu[c * F + kcs * 8] = *(const f16x8*)&Mtu[c * F + kc * 8];
        *(f16x8*)&Lr[c * F + kcs * 8] = *(const f16x8*)&Mtr[c * F + kc * 8];
    }
    __syncthreads();

    int lane = threadIdx.x & 63;
    int wave = threadIdx.x >> 6;
    int lo = lane & 15, hi = lane >> 4;

    float cb[8];
#pragma unroll
    for (int t = 0; t < 8; t++) cb[t] = bn[t * 16 + lo] + bias[t * 16 + lo];

    for (int tile = blockIdx.x; tile < ntiles; tile += 256) {
        int row0 = tile * 256 + wave * 16;
        if (row0 >= n) continue;
        int arow = row0 + lo;
        if (arow > n - 1) arow = n - 1;
        const f16_t* pf = featb + (size_t)arow * F + hi * 8;
        const f16_t* pu = aggu + (size_t)arow * F + hi * 8;
        const f16_t* pr = aggr + (size_t)arow * F + hi * 8;

        f32x4 acc[8];
#pragma unroll
        for (int t = 0; t < 8; t++) acc[t] = (f32x4){0.f, 0.f, 0.f, 0.f};

#pragma unroll
        for (int ks = 0; ks < 4; ks++) {
            f16x8 a1 = *(const f16x8*)(pf + ks * 32);
            f16x8 a2 = *(const f16x8*)(pu + ks * 32);
            f16x8 a3 = *(const f16x8*)(pr + ks * 32);
#pragma unroll
            for (int t = 0; t < 8; t++) {
                int c = t * 16 + lo;
                int kcs = (ks * 4 + hi) ^ lo;
                f16x8 bs = *(const f16x8*)&Ls[c * F + kcs * 8];
                f16x8 bu = *(const f16x8*)&Lu[c * F + kcs * 8];
                f16x8 br = *(const f16x8*)&Lr[c * F + kcs * 8];
                acc[t] = __builtin_amdgcn_mfma_f32_16x16x32_f16(a1, bs, acc[t], 0, 0, 0);
                acc[t] = __builtin_amdgcn_mfma_f32_16x16x32_f16(a2, bu, acc[t], 0, 0, 0);
                acc[t] = __builtin_amdgcn_mfma_f32_16x16x32_f16(a3, br, acc[t], 0, 0, 0);
            }
        }

#pragma unroll
        for (int j = 0; j < 4; j++) {
            int r = row0 + hi * 4 + j;
            if (r < n) {
                float* op = out + (size_t)r * F + lo;
#pragma unroll
                for (int t = 0; t < 8; t++) op[t * 16] = acc[t][j] + cb[t];
            }
        }
    }
}

// ---------------- launch ----------------

extern "C" void kernel_launch(void* const* d_in, const int* in_sizes, int n_in,
                              void* d_out, int out_size, void* d_ws, size_t ws_size,
                              hipStream_t stream) {
    const float* feat   = (const float*)d_in[0];
    const int*   src_u  = (const int*)d_in[1];
    const int*   dst_u  = (const int*)d_in[2];
    const int*   src_r  = (const int*)d_in[3];
    const int*   dst_r  = (const int*)d_in[4];
    const float* W_self = (const float*)d_in[5];
    const float* W_u    = (const float*)d_in[6];
    const float* a_l_u  = (const float*)d_in[7];
    const float* a_r_u  = (const float*)d_in[8];
    const float* W_r    = (const float*)d_in[9];
    const float* a_l_r  = (const float*)d_in[10];
    const float* a_r_r  = (const float*)d_in[11];
    const float* W_ngh  = (const float*)d_in[12];
    const float* b_ngh  = (const float*)d_in[13];
    const float* bias   = (const float*)d_in[14];
    float* out = (float*)d_out;

    const int N  = in_sizes[0] / F;
    const int Eu = in_sizes[1];
    const int Er = in_sizes[3];
    const int Et = Eu + Er;
    const int twoN = 2 * N;
    const int nbk = (twoN + BPB - 1) >> SHIFT;   // buckets (<= NBS)

    char* ws = (char*)d_ws;
    size_t off = 0;
    auto alloc = [&](size_t bytes) -> void* {
        void* p = ws + off;
        off = (off + bytes + 255) & ~(size_t)255;
        return p;
    };
    f16_t* featb = (f16_t*)alloc((size_t)N * F * 2);
    f16_t* aggu  = (f16_t*)alloc((size_t)N * F * 2);
    f16_t* aggr  = (f16_t*)alloc((size_t)N * F * 2);
    f16_t* Mt_u  = (f16_t*)alloc((size_t)F * F * 2);
    f16_t* Mt_r  = (f16_t*)alloc((size_t)F * F * 2);
    f16_t* Wt_s  = (f16_t*)alloc((size_t)F * F * 2);
    float* wlu = (float*)alloc((size_t)F * 4);
    float* wru = (float*)alloc((size_t)F * 4);
    float* wlr = (float*)alloc((size_t)F * 4);
    float* wrr = (float*)alloc((size_t)F * 4);
    float* elu = (float*)alloc((size_t)N * 4);
    float* eru = (float*)alloc((size_t)N * 4);
    float* elr = (float*)alloc((size_t)N * 4);
    float* err_ = (float*)alloc((size_t)N * 4);
    int* cnt_bb = (int*)alloc((size_t)256 * NBS * 4);
    int* btot   = (int*)alloc((size_t)NBS * 4);
    int* bbase  = (int*)alloc((size_t)(NBS + 1) * 4);
    int* rp2    = (int*)alloc(((size_t)twoN + 1) * 4);
    uint2* bucketed = (uint2*)alloc((size_t)Et * 8);
    int* csr2   = (int*)alloc((size_t)Et * 4);

    prep_mats<<<388, 128, 0, stream>>>(W_u, W_r, W_self, W_ngh,
                                       a_l_u, a_r_u, a_l_r, a_r_r,
                                       Mt_u, Mt_r, Wt_s, wlu, wru, wlr, wrr);

    const int chunk = (Et + 255) / 256;
    int castBlocks = (N + 63) / 64;
    cast_p1a<<<256 + castBlocks, 256, 0, stream>>>(
        feat, wlu, wru, wlr, wrr, featb, elu, eru, elr, err_,
        dst_u, dst_r, cnt_bb, Eu, Et, N, chunk, N, nbk);

    scan_bb1<<<nbk, 256, 0, stream>>>(cnt_bb, btot, nbk);
    scan_bb2<<<1, 512, 0, stream>>>(btot, bbase, rp2, nbk, twoN, Et);
    p1b_scatter<<<256, 256, 0, stream>>>(src_u, dst_u, src_r, dst_r,
                                         cnt_bb, bbase, bucketed,
                                         Eu, Et, N, chunk, nbk);
    p2_build<<<nbk, 256, 0, stream>>>(bucketed, bbase, rp2, csr2, twoN);

    aggregate_fused<<<(N + 3) / 4, 256, 0, stream>>>(featb, elu, eru, elr, err_,
                                                     rp2, csr2, aggu, aggr, N);
    int ntiles = (N + 255) / 256;
    mfma_final3<<<256, 1024, 0, stream>>>(featb, aggu, aggr,
                                          Wt_s, Mt_u, Mt_r,
                                          b_ngh, bias, out, N, ntiles);
}